// Round 7
// baseline (761.984 us; speedup 1.0000x reference)
//
#include <hip/hip_runtime.h>
#include <hip/hip_bf16.h>
#include <stdint.h>

#define HID 1024
#define NB 32
#define NS 2048

typedef short v8s __attribute__((ext_vector_type(8)));    // 8 x bf16 bits
typedef float v16f __attribute__((ext_vector_type(16)));  // 32x32 MFMA acc
typedef const __attribute__((address_space(1))) void* gas_t;
typedef __attribute__((address_space(3))) void* las_t;

// direct global->LDS DMA, 16B per lane. LDS dest = wave-uniform base + lane*16.
__device__ __forceinline__ void gload16(const void* g, void* l){
  __builtin_amdgcn_global_load_lds((gas_t)g, (las_t)l, 16, 0, 0);
}

// packed f32x2 -> bf16x2 (RNE), 1 VALU op. Pair-order effects cancel: keys and
// Wk get the identical k-permutation -> dot product invariant.
__device__ __forceinline__ unsigned cvt2(float a, float b){
  unsigned r;
  asm("v_cvt_pk_bf16_f32 %0, %1, %2" : "=v"(r) : "v"(a), "v"(b));
  return r;
}

__device__ __forceinline__ uint4 pack8(const float4& a, const float4& b){
  uint4 r;
  r.x = cvt2(a.x, a.y);
  r.y = cvt2(a.z, a.w);
  r.z = cvt2(b.x, b.y);
  r.w = cvt2(b.z, b.w);
  return r;
}

// ---------------- K0: fp32 -> bf16 streaming convert ----------------
__global__ __launch_bounds__(256) void k_conv(const float* __restrict__ src,
                                              ushort* __restrict__ dst, int n8){
  int i0 = (blockIdx.x << 8) + threadIdx.x;
  int stride = gridDim.x << 8;
  for (int i = i0; i < n8; i += stride){
    const float4* s = (const float4*)(src + (size_t)i*8);
    float4 a = s[0], b = s[1];
    *(uint4*)(dst + (size_t)i*8) = pack8(a, b);
  }
}

// ---------------- K1: q_proj (fp32) + zero scores ----------------
__global__ __launch_bounds__(256) void k_qproj(const float* __restrict__ query,
                                               const float* __restrict__ Wq,
                                               float* __restrict__ qp,
                                               float* __restrict__ scores){
  int tid = threadIdx.x;
  int gw = ((blockIdx.x << 8) + tid) >> 6;   // wave id 0..32767
  int lane = tid & 63;
  int b = gw >> 10, o = gw & 1023;
  const float* qr = query + b*HID;
  const float* wr = Wq + (size_t)o*HID;
  float p = 0.f;
#pragma unroll
  for (int i = 0; i < 16; ++i){
    int h = lane + (i << 6);
    p += qr[h]*wr[h];
  }
#pragma unroll
  for (int m = 32; m >= 1; m >>= 1) p += __shfl_xor(p, m, 64);
  if (lane == 0) qp[gw] = p;
  if (tid < 8) scores[(blockIdx.x << 3) + tid] = 0.f;
}

// ---------------- K3 (main): 2-phase counted-vmcnt fused GEMM+tanh+V-dot ----------
// 128x128 tile, BK=64 bf16, DOUBLE-buffered 64KB LDS, global_load_lds width 16.
// Pipeline: stage(kt+2) issued after compute(kt); raw s_barrier; counted
// s_waitcnt vmcnt(8) so one full tile (8 DMAs/wave) stays in flight across the
// barrier (T3/T4). XOR chunk swizzle carried on the pre-swizzled global source;
// ds_read applies the same XOR (both-sides involution).
__global__ __launch_bounds__(256, 2) void k_scores2(const ushort* __restrict__ keysb,
                                                    const ushort* __restrict__ Wkb,
                                                    const float* __restrict__ qp,
                                                    const float* __restrict__ V,
                                                    float* __restrict__ scores){
  __shared__ uint4 Ab[2][1024];   // 32KB: [buf][row*8+physchunk], 16B slots
  __shared__ uint4 Bb[2][1024];
  int bid = blockIdx.x;
  // XCD-chunked bijective swizzle (4096 % 8 == 0)
  int v = ((bid & 7) << 9) | (bid >> 3);
  int mt = v >> 3, nt = v & 7;
  int m0 = mt << 7, n0 = nt << 7;
  int b = m0 >> 11;
  int tid = threadIdx.x;
  int lane = tid & 63;
  int wid = tid >> 6;
  int wm = wid >> 1, wn = wid & 1;  // 2x2 waves, 64x64 each
  int l31 = lane & 31, hi = lane >> 5;

  v16f acc[2][2] = {};

  auto stage = [&](int kt, int bsel){
#pragma unroll
    for (int j = 0; j < 4; ++j){
      int s = (wid << 8) + (j << 6) + lane;    // slot 0..1023
      int row = s >> 3;
      int lc = (s & 7) ^ (row & 7);            // logical k-chunk for phys slot
      size_t goff = (size_t)row*HID + (kt << 6) + (lc << 3);
      char* lb = (char*)(&Ab[bsel][0]) + (((wid << 2) + j) << 10);
      gload16(keysb + (size_t)m0*HID + goff, lb);
      char* lb2 = (char*)(&Bb[bsel][0]) + (((wid << 2) + j) << 10);
      gload16(Wkb + (size_t)n0*HID + goff, lb2);
    }
  };

  stage(0, 0);
  stage(1, 1);                         // 16 DMAs outstanding
  for (int kt = 0; kt < 16; ++kt){
    int bs = kt & 1;
    // wait for tile kt's 8 DMAs (oldest); keep tile kt+1's 8 in flight
    if (kt < 15) asm volatile("s_waitcnt vmcnt(8)" ::: "memory");
    else         asm volatile("s_waitcnt vmcnt(0)" ::: "memory");
    __builtin_amdgcn_sched_barrier(0);
    __builtin_amdgcn_s_barrier();      // raw: no compiler vmcnt(0) drain
    __builtin_amdgcn_sched_barrier(0);
#pragma unroll
    for (int ks = 0; ks < 4; ++ks){
      int kg = (ks << 1) + hi;                 // logical k-chunk 0..7
      int ra = (wm << 6) + l31;
      int rb = (wn << 6) + l31;
      int offA = ra*128 + ((kg ^ (ra & 7)) << 4);
      int offB = rb*128 + ((kg ^ (rb & 7)) << 4);
      const char* Abase = (const char*)(&Ab[bs][0]);
      const char* Bbase = (const char*)(&Bb[bs][0]);
      v8s a0 = __builtin_bit_cast(v8s, *(const uint4*)(Abase + offA));
      v8s a1 = __builtin_bit_cast(v8s, *(const uint4*)(Abase + offA + 4096));
      v8s b0 = __builtin_bit_cast(v8s, *(const uint4*)(Bbase + offB));
      v8s b1 = __builtin_bit_cast(v8s, *(const uint4*)(Bbase + offB + 4096));
      acc[0][0] = __builtin_amdgcn_mfma_f32_32x32x16_bf16(a0, b0, acc[0][0], 0, 0, 0);
      acc[0][1] = __builtin_amdgcn_mfma_f32_32x32x16_bf16(a0, b1, acc[0][1], 0, 0, 0);
      acc[1][0] = __builtin_amdgcn_mfma_f32_32x32x16_bf16(a1, b0, acc[1][0], 0, 0, 0);
      acc[1][1] = __builtin_amdgcn_mfma_f32_32x32x16_bf16(a1, b1, acc[1][1], 0, 0, 0);
    }
    asm volatile("s_waitcnt lgkmcnt(0)" ::: "memory");   // my reads of buf bs retired
    __builtin_amdgcn_sched_barrier(0);
    __builtin_amdgcn_s_barrier();      // all waves done reading buf bs
    __builtin_amdgcn_sched_barrier(0);
    if (kt < 14) stage(kt + 2, bs);    // overwrite buf bs for tile kt+2
  }

  // epilogue: scores[row] += sum_o V[o]*tanh(qp[b][o] + kproj)  (validated)
  float qpv[2], Vv[2];
#pragma unroll
  for (int ni = 0; ni < 2; ++ni){
    int o = n0 + (wn << 6) + (ni << 5) + l31;
    qpv[ni] = qp[(b << 10) + o];
    Vv[ni] = V[o];
  }
#pragma unroll
  for (int mi = 0; mi < 2; ++mi){
#pragma unroll
    for (int r = 0; r < 16; ++r){
      float sp = 0.f;
#pragma unroll
      for (int ni = 0; ni < 2; ++ni){
        float x = qpv[ni] + acc[mi][ni][r];
        float e = __expf(2.f*x);
        sp += Vv[ni]*(1.f - 2.f/(e + 1.f));
      }
#pragma unroll
      for (int m = 16; m >= 1; m >>= 1) sp += __shfl_xor(sp, m, 64);
      if (l31 == 0){
        int row = m0 + (wm << 6) + (mi << 5) + (r & 3) + ((r >> 2) << 3) + (hi << 2);
        atomicAdd(&scores[row], sp);
      }
    }
  }
}

// ---------------- K4: softmax per batch + zero context region ----------------
__global__ __launch_bounds__(256) void k_softmax(const float* __restrict__ scores,
                                                 float* __restrict__ out){
  int b = blockIdx.x; int tid = threadIdx.x;
  __shared__ float red[8];
  const float* srow = scores + b*NS;
  float vv[8];
  float mx = -1e30f;
#pragma unroll
  for (int i = 0; i < 8; ++i){ vv[i] = srow[tid + (i << 8)]; mx = fmaxf(mx, vv[i]); }
#pragma unroll
  for (int m = 32; m >= 1; m >>= 1) mx = fmaxf(mx, __shfl_xor(mx, m, 64));
  int wid = tid >> 6, lane = tid & 63;
  if (lane == 0) red[wid] = mx;
  __syncthreads();
  mx = fmaxf(fmaxf(red[0], red[1]), fmaxf(red[2], red[3]));
  float s = 0.f;
#pragma unroll
  for (int i = 0; i < 8; ++i){ vv[i] = __expf(vv[i] - mx); s += vv[i]; }
#pragma unroll
  for (int m = 32; m >= 1; m >>= 1) s += __shfl_xor(s, m, 64);
  if (lane == 0) red[4 + wid] = s;
  __syncthreads();
  s = red[4] + red[5] + red[6] + red[7];
  float inv = 1.f/s;
  float* wout = out + NB*HID + b*NS;
#pragma unroll
  for (int i = 0; i < 8; ++i) wout[tid + (i << 8)] = vv[i]*inv;
  float4* ctx = (float4*)(out + b*HID);
  ctx[tid] = make_float4(0.f, 0.f, 0.f, 0.f);
}

// ---------------- K5: context = weights @ keys (fp32, coalesced rows) ----------------
// block = (b, sc): 64 s-rows; 256 threads each own a float4 h-chunk (full 1024 h).
__global__ __launch_bounds__(256) void k_context2(const float* __restrict__ keys,
                                                  const float* __restrict__ w,
                                                  float* __restrict__ ctx){
  __shared__ float ws[64];
  int blk = blockIdx.x;                 // 1024 = 32 b x 32 sc
  int b = blk >> 5, sc = blk & 31;
  int s0 = sc << 6;
  int tid = threadIdx.x;
  if (tid < 64) ws[tid] = w[b*NS + s0 + tid];
  __syncthreads();
  const float4* kp = (const float4*)(keys + ((size_t)b*NS + s0)*HID) + tid;
  float4 a = make_float4(0.f, 0.f, 0.f, 0.f);
#pragma unroll 8
  for (int s = 0; s < 64; ++s){
    float4 kv = kp[(size_t)s*256];
    float wv = ws[s];
    a.x += wv*kv.x; a.y += wv*kv.y; a.z += wv*kv.z; a.w += wv*kv.w;
  }
  float* o = ctx + b*HID + (tid << 2);
  atomicAdd(o, a.x); atomicAdd(o + 1, a.y); atomicAdd(o + 2, a.z); atomicAdd(o + 3, a.w);
}

extern "C" void kernel_launch(void* const* d_in, const int* in_sizes, int n_in,
                              void* d_out, int out_size, void* d_ws, size_t ws_size,
                              hipStream_t stream){
  const float* query = (const float*)d_in[0];
  const float* keys  = (const float*)d_in[1];
  const float* Wq    = (const float*)d_in[2];
  const float* Wk    = (const float*)d_in[3];
  const float* V     = (const float*)d_in[4];
  float* out = (float*)d_out;
  float* qp = (float*)d_ws;                       // 32K f32
  float* scores = qp + NB*HID;                    // 64K f32
  ushort* keysb = (ushort*)((char*)d_ws + ((size_t)NB*HID + (size_t)NB*NS)*4);
  ushort* Wkb = keysb + (size_t)NB*NS*HID;

  hipLaunchKernelGGL(k_qproj, dim3(8192), dim3(256), 0, stream, query, Wq, qp, scores);
  hipLaunchKernelGGL(k_conv, dim3(2048), dim3(256), 0, stream, keys, keysb, NB*NS*HID/8);
  hipLaunchKernelGGL(k_conv, dim3(256),  dim3(256), 0, stream, Wk, Wkb, HID*HID/8);
  hipLaunchKernelGGL(k_scores2, dim3(4096), dim3(256), 0, stream, keysb, Wkb, qp, V, scores);
  hipLaunchKernelGGL(k_softmax, dim3(32), dim3(256), 0, stream, scores, out);
  hipLaunchKernelGGL(k_context2, dim3(1024), dim3(256), 0, stream, keys, out + NB*HID, out);
}